// Round 1
// baseline (634.990 us; speedup 1.0000x reference)
//
#include <hip/hip_runtime.h>

#define EPS 1e-6f

typedef __attribute__((ext_vector_type(8))) __bf16 bf16x8;
typedef __attribute__((ext_vector_type(4))) float f32x4;
typedef __attribute__((ext_vector_type(4))) unsigned short us4v;
typedef __attribute__((ext_vector_type(8))) unsigned short us8v;

__device__ inline unsigned short f2bf(float f) {
  unsigned int u = __builtin_bit_cast(unsigned int, f);
  unsigned int r = (u + 0x7fffu + ((u >> 16) & 1u)) >> 16;
  return (unsigned short)r;
}
__device__ inline float bf2f(unsigned short s) {
  unsigned int u = ((unsigned int)s) << 16;
  return __builtin_bit_cast(float, u);
}

// ---------------------------------------------------------------------------
// Projection GEMM: Y[i][j] = act( sum_d X[i][d] * W[j][d] + bias[j] )
// X: 16384 x 1024 (fp32 for MODE 0/1/2, bf16 for MODE 3), W: 1024 x 1024 fp32.
// MODE 0: phi (elu+1), store bf16 row-major           (q projection)
// MODE 1: phi,         store bf16 transposed per head (k -> kt[bh][d][m])
// MODE 2: identity,    store bf16 transposed per head (v -> vt[bh][e][m])
// MODE 3: identity,    store fp32 row-major           (output projection)
// ---------------------------------------------------------------------------
template <int MODE>
__global__ __launch_bounds__(256) void proj_gemm(const void* __restrict__ Xv,
                                                 const float* __restrict__ W,
                                                 const float* __restrict__ bias,
                                                 void* __restrict__ Yv) {
  __shared__ unsigned short Xs[128 * 72];  // 64 cols + pad 8
  __shared__ unsigned short Ws[128 * 72];

  const int t = threadIdx.x;
  const int wave = t >> 6, lane = t & 63;
  const int q4 = lane >> 4, l16 = lane & 15;
  const int wm = wave & 1, wn = wave >> 1;
  const int rowBase = blockIdx.y * 128;
  const int colBase = blockIdx.x * 128;

  f32x4 acc[4][4];
#pragma unroll
  for (int i = 0; i < 4; i++)
#pragma unroll
    for (int j = 0; j < 4; j++) acc[i][j] = (f32x4){0.f, 0.f, 0.f, 0.f};

  for (int k0 = 0; k0 < 1024; k0 += 64) {
    // ---- stage X tile ----
    if (MODE == 3) {
      const unsigned short* X = (const unsigned short*)Xv;
#pragma unroll
      for (int i = 0; i < 4; i++) {
        int idx = t + 256 * i;              // 0..1023 chunks of 8
        int r = idx >> 3, c8 = (idx & 7) << 3;
        us8v v = *(const us8v*)(X + (size_t)(rowBase + r) * 1024 + k0 + c8);
        *(us8v*)(Xs + r * 72 + c8) = v;
      }
    } else {
      const float* X = (const float*)Xv;
#pragma unroll
      for (int i = 0; i < 8; i++) {
        int idx = t + 256 * i;              // 0..2047 float4 chunks
        int r = idx >> 4, c4 = (idx & 15) << 2;
        float4 v = *(const float4*)(X + (size_t)(rowBase + r) * 1024 + k0 + c4);
        us4v p;
        p[0] = f2bf(v.x); p[1] = f2bf(v.y); p[2] = f2bf(v.z); p[3] = f2bf(v.w);
        *(us4v*)(Xs + r * 72 + c4) = p;
      }
    }
    // ---- stage W tile (always fp32) ----
#pragma unroll
    for (int i = 0; i < 8; i++) {
      int idx = t + 256 * i;
      int r = idx >> 4, c4 = (idx & 15) << 2;
      float4 v = *(const float4*)(W + (size_t)(colBase + r) * 1024 + k0 + c4);
      us4v p;
      p[0] = f2bf(v.x); p[1] = f2bf(v.y); p[2] = f2bf(v.z); p[3] = f2bf(v.w);
      *(us4v*)(Ws + r * 72 + c4) = p;
    }
    __syncthreads();

    // ---- MFMA over BK=64 (2 K-steps of 32) ----
#pragma unroll
    for (int ks = 0; ks < 2; ks++) {
      bf16x8 af[4], bfr[4];
#pragma unroll
      for (int i = 0; i < 4; i++)
        af[i] = *(const bf16x8*)(Xs + (wm * 64 + i * 16 + l16) * 72 + ks * 32 + q4 * 8);
#pragma unroll
      for (int j = 0; j < 4; j++)
        bfr[j] = *(const bf16x8*)(Ws + (wn * 64 + j * 16 + l16) * 72 + ks * 32 + q4 * 8);
#pragma unroll
      for (int i = 0; i < 4; i++)
#pragma unroll
        for (int j = 0; j < 4; j++)
          acc[i][j] = __builtin_amdgcn_mfma_f32_16x16x32_bf16(af[i], bfr[j], acc[i][j], 0, 0, 0);
    }
    __syncthreads();
  }

  // ---- epilogue ----
#pragma unroll
  for (int i = 0; i < 4; i++) {
#pragma unroll
    for (int j = 0; j < 4; j++) {
      int col = colBase + wn * 64 + j * 16 + l16;
      float bv = bias[col];
#pragma unroll
      for (int r = 0; r < 4; r++) {
        int row = rowBase + wm * 64 + i * 16 + q4 * 4 + r;
        float y = acc[i][j][r] + bv;
        if (MODE == 0 || MODE == 1) y = (y > 0.f) ? (y + 1.f) : __expf(y);
        if (MODE == 0) {
          ((unsigned short*)Yv)[(size_t)row * 1024 + col] = f2bf(y);
        } else if (MODE == 1 || MODE == 2) {
          int b = row >> 12, m = row & 4095;
          int h = col >> 6, d = col & 63;
          ((unsigned short*)Yv)[(((size_t)((b * 16 + h) * 64 + d)) << 12) + m] = f2bf(y);
        } else {
          ((float*)Yv)[(size_t)row * 1024 + col] = y;
        }
      }
    }
  }
}

// ---------------------------------------------------------------------------
// kv_t[bh][e][d] = sum_m v[m][e] * k[m][d]   (atomic split-K accumulation, S=16)
// A = vt rows (e, K=m), B = kt rows (d, K=m). One wave per block.
// ---------------------------------------------------------------------------
__global__ __launch_bounds__(64) void kv_kernel(const unsigned short* __restrict__ kt,
                                                const unsigned short* __restrict__ vt,
                                                float* __restrict__ kvacc) {
  const int bh = blockIdx.x >> 4;
  const int s = blockIdx.x & 15;
  const int lane = threadIdx.x;
  const int q4 = lane >> 4, l16 = lane & 15;
  const size_t base = (size_t)bh * 64 * 4096;
  const unsigned short* ktb = kt + base;
  const unsigned short* vtb = vt + base;

  f32x4 acc[4][4];
#pragma unroll
  for (int i = 0; i < 4; i++)
#pragma unroll
    for (int j = 0; j < 4; j++) acc[i][j] = (f32x4){0.f, 0.f, 0.f, 0.f};

  const int m0beg = s * 256;
  for (int m0 = m0beg; m0 < m0beg + 256; m0 += 32) {
    bf16x8 af[4], bfr[4];
#pragma unroll
    for (int i = 0; i < 4; i++)
      af[i] = *(const bf16x8*)(vtb + (size_t)(i * 16 + l16) * 4096 + m0 + q4 * 8);
#pragma unroll
    for (int j = 0; j < 4; j++)
      bfr[j] = *(const bf16x8*)(ktb + (size_t)(j * 16 + l16) * 4096 + m0 + q4 * 8);
#pragma unroll
    for (int i = 0; i < 4; i++)
#pragma unroll
      for (int j = 0; j < 4; j++)
        acc[i][j] = __builtin_amdgcn_mfma_f32_16x16x32_bf16(af[i], bfr[j], acc[i][j], 0, 0, 0);
  }

  float* dst = kvacc + (size_t)bh * 64 * 64;
#pragma unroll
  for (int i = 0; i < 4; i++)
#pragma unroll
    for (int j = 0; j < 4; j++)
#pragma unroll
      for (int r = 0; r < 4; r++) {
        int e = i * 16 + q4 * 4 + r;
        int d = j * 16 + l16;
        atomicAdd(dst + e * 64 + d, acc[i][j][r]);
      }
}

// z[bh][d] = sum_m kt[bh][d][m]
__global__ __launch_bounds__(64) void z_kernel(const unsigned short* __restrict__ kt,
                                               float* __restrict__ z) {
  const int bh = blockIdx.x;
  const int d = threadIdx.x;
  const unsigned short* row = kt + ((size_t)bh * 64 + d) * 4096;
  float s = 0.f;
  for (int m = 0; m < 4096; m += 8) {
    us8v v = *(const us8v*)(row + m);
#pragma unroll
    for (int j = 0; j < 8; j++) s += bf2f(v[j]);
  }
  z[bh * 64 + d] = s;
}

// ---------------------------------------------------------------------------
// attn[b][n][h*64+e] = (sum_d q[n][d] kv[d][e]) / (q[n]·z + eps), bf16 out.
// Block: one (b,h) head x 256 rows of n. 4 waves, each 64 rows x 64 cols.
// ---------------------------------------------------------------------------
__global__ __launch_bounds__(256) void attn_kernel(const unsigned short* __restrict__ q,
                                                   const float* __restrict__ kvacc,
                                                   const float* __restrict__ z,
                                                   unsigned short* __restrict__ attn) {
  __shared__ unsigned short kvs[64 * 72];
  __shared__ float zs[64];
  __shared__ float invden[256];

  const int bid = blockIdx.x;
  const int bh = bid >> 4, nc = bid & 15;
  const int b = bh >> 4, h = bh & 15;
  const int n0 = nc * 256;
  const int t = threadIdx.x;
  const int wave = t >> 6, lane = t & 63;
  const int q4 = lane >> 4, l16 = lane & 15;

  // kv (fp32) -> bf16 LDS, layout kvs[e][d]
  const float* kvb = kvacc + (size_t)bh * 4096;
#pragma unroll
  for (int i = 0; i < 16; i++) {
    int idx = t + 256 * i;  // 0..4095
    int e = idx >> 6, d = idx & 63;
    kvs[e * 72 + d] = f2bf(kvb[idx]);
  }
  if (t < 64) zs[t] = z[bh * 64 + t];
  __syncthreads();

  // denominator for row n0 + t
  {
    const unsigned short* qrow = q + ((size_t)(b * 4096 + n0 + t)) * 1024 + h * 64;
    float s = 0.f;
#pragma unroll
    for (int d0 = 0; d0 < 64; d0 += 8) {
      us8v v = *(const us8v*)(qrow + d0);
#pragma unroll
      for (int j = 0; j < 8; j++) s += bf2f(v[j]) * zs[d0 + j];
    }
    invden[t] = 1.0f / (s + EPS);
  }
  __syncthreads();

  f32x4 acc[4][4];
#pragma unroll
  for (int i = 0; i < 4; i++)
#pragma unroll
    for (int j = 0; j < 4; j++) acc[i][j] = (f32x4){0.f, 0.f, 0.f, 0.f};

  const unsigned short* qb = q + ((size_t)(b * 4096 + n0 + wave * 64)) * 1024 + h * 64;
#pragma unroll
  for (int ks = 0; ks < 2; ks++) {
    bf16x8 af[4], bfr[4];
#pragma unroll
    for (int i = 0; i < 4; i++)
      af[i] = *(const bf16x8*)(qb + (size_t)(i * 16 + l16) * 1024 + ks * 32 + q4 * 8);
#pragma unroll
    for (int j = 0; j < 4; j++)
      bfr[j] = *(const bf16x8*)(kvs + (j * 16 + l16) * 72 + ks * 32 + q4 * 8);
#pragma unroll
    for (int i = 0; i < 4; i++)
#pragma unroll
      for (int j = 0; j < 4; j++)
        acc[i][j] = __builtin_amdgcn_mfma_f32_16x16x32_bf16(af[i], bfr[j], acc[i][j], 0, 0, 0);
  }

  unsigned short* ab = attn + ((size_t)(b * 4096 + n0 + wave * 64)) * 1024 + h * 64;
#pragma unroll
  for (int i = 0; i < 4; i++)
#pragma unroll
    for (int j = 0; j < 4; j++)
#pragma unroll
      for (int r = 0; r < 4; r++) {
        int rowl = i * 16 + q4 * 4 + r;        // within wave (0..63)
        int nl = wave * 64 + rowl;             // within block (0..255)
        int e = j * 16 + l16;
        float y = acc[i][j][r] * invden[nl];
        ab[(size_t)rowl * 1024 + e] = f2bf(y);
      }
}

// ---------------------------------------------------------------------------
extern "C" void kernel_launch(void* const* d_in, const int* in_sizes, int n_in,
                              void* d_out, int out_size, void* d_ws, size_t ws_size,
                              hipStream_t stream) {
  const float* queries = (const float*)d_in[0];
  const float* keys    = (const float*)d_in[1];
  const float* values  = (const float*)d_in[2];
  const float* wq = (const float*)d_in[3];
  const float* bq = (const float*)d_in[4];
  const float* wk = (const float*)d_in[5];
  const float* bk = (const float*)d_in[6];
  const float* wv = (const float*)d_in[7];
  const float* bv = (const float*)d_in[8];
  const float* wo = (const float*)d_in[9];
  const float* bo = (const float*)d_in[10];

  char* ws = (char*)d_ws;
  const size_t QB = (size_t)16384 * 1024 * 2;  // 33.55 MB bf16 buffer
  unsigned short* q_buf  = (unsigned short*)(ws);
  unsigned short* kt_buf = (unsigned short*)(ws + QB);
  unsigned short* vt_buf = (unsigned short*)(ws + 2 * QB);
  float* kv_buf = (float*)(ws + 3 * QB);                  // 64*64*64 fp32
  float* z_buf  = (float*)(ws + 3 * QB + 262144 * 4);     // 64*64 fp32
  unsigned short* attn_buf = kt_buf;                      // reuse (kt dead after kv/z)

  dim3 ggrid(8, 128), gblk(256);
  proj_gemm<0><<<ggrid, gblk, 0, stream>>>((const void*)queries, wq, bq, (void*)q_buf);
  proj_gemm<1><<<ggrid, gblk, 0, stream>>>((const void*)keys, wk, bk, (void*)kt_buf);
  proj_gemm<2><<<ggrid, gblk, 0, stream>>>((const void*)values, wv, bv, (void*)vt_buf);

  hipMemsetAsync((void*)kv_buf, 0, (262144 + 4096) * sizeof(float), stream);
  z_kernel<<<64, 64, 0, stream>>>(kt_buf, z_buf);
  kv_kernel<<<1024, 64, 0, stream>>>(kt_buf, vt_buf, kv_buf);
  attn_kernel<<<1024, 256, 0, stream>>>(q_buf, kv_buf, z_buf, attn_buf);

  proj_gemm<3><<<ggrid, gblk, 0, stream>>>((const void*)attn_buf, wo, bo, d_out);
}

// Round 2
// 467.649 us; speedup vs baseline: 1.3578x; 1.3578x over previous
//
#include <hip/hip_runtime.h>

#define EPS 1e-6f

typedef __attribute__((ext_vector_type(8))) __bf16 bf16x8;
typedef __attribute__((ext_vector_type(4))) float f32x4;
typedef __attribute__((ext_vector_type(4))) unsigned short us4v;
typedef __attribute__((ext_vector_type(8))) unsigned short us8v;
typedef unsigned short us;

__device__ inline us f2bf(float f) {
  unsigned int u = __builtin_bit_cast(unsigned int, f);
  unsigned int r = (u + 0x7fffu + ((u >> 16) & 1u)) >> 16;
  return (us)r;
}
__device__ inline float bf2f(us s) {
  unsigned int u = ((unsigned int)s) << 16;
  return __builtin_bit_cast(float, u);
}

__device__ inline void gl_lds16(const us* g, us* l) {
  __builtin_amdgcn_global_load_lds(
      (const __attribute__((address_space(1))) unsigned int*)g,
      (__attribute__((address_space(3))) unsigned int*)l, 16, 0, 0);
}

// ---------------------------------------------------------------------------
// fp32 -> bf16 convert (RNE), n elements (multiple of 2048). grid = n/2048.
// ---------------------------------------------------------------------------
__global__ __launch_bounds__(256) void conv_bf16(const float* __restrict__ s,
                                                 us* __restrict__ d) {
  int idx = blockIdx.x * 256 + threadIdx.x;
  size_t base = (size_t)idx * 8;
  float4 a = *(const float4*)(s + base);
  float4 b = *(const float4*)(s + base + 4);
  us8v o;
  o[0] = f2bf(a.x); o[1] = f2bf(a.y); o[2] = f2bf(a.z); o[3] = f2bf(a.w);
  o[4] = f2bf(b.x); o[5] = f2bf(b.y); o[6] = f2bf(b.z); o[7] = f2bf(b.w);
  *(us8v*)(d + base) = o;
}

// ---------------------------------------------------------------------------
// Projection GEMM, all-bf16, m97-style: global_load_lds 16B staging into
// unpadded XOR-swizzled LDS, 128x128 tile, BK=64, mfma 16x16x32.
// Y[i][j] = act( sum_k X[i][k] * W[j][k] + bias[j] )
// MODE 0: phi (elu+1), store bf16 row-major           (q projection)
// MODE 1: phi,         store bf16 transposed per head (k -> kt[bh][d][m])
// MODE 2: identity,    store bf16 transposed per head (v -> vt[bh][e][m])
// MODE 3: identity,    store fp32 row-major           (output projection)
// grid: 1024 blocks 1-D; col = bid>>7, row = bid&127 so the 8 col-blocks of a
// row-group share bid%8 (same XCD) -> X row-tiles hit one L2.
// ---------------------------------------------------------------------------
template <int MODE>
__global__ __launch_bounds__(256) void proj_gemm(const us* __restrict__ X,
                                                 const us* __restrict__ W,
                                                 const float* __restrict__ bias,
                                                 void* __restrict__ Yv) {
  __shared__ alignas(16) us Xs[128 * 64];
  __shared__ alignas(16) us Ws[128 * 64];

  const int t = threadIdx.x;
  const int wave = t >> 6, lane = t & 63;
  const int q4 = lane >> 4, l16 = lane & 15;
  const int wm = wave & 1, wn = wave >> 1;
  const int bid = blockIdx.x;
  const int colBase = (bid >> 7) << 7;
  const int rowBase = (bid & 127) << 7;

  // staging geometry: thread covers chunk (i*256 + t); row = i*32 + t>>3,
  // global chunk = (t&7) ^ (row&7)  (row&7 == (t>>3)&7 since 32i % 8 == 0)
  const int srow0 = t >> 3;
  const int spos = (t & 7) ^ (srow0 & 7);
  const us* Xg = X + (size_t)rowBase * 1024 + (size_t)srow0 * 1024 + spos * 8;
  const us* Wg = W + (size_t)colBase * 1024 + (size_t)srow0 * 1024 + spos * 8;

  f32x4 acc[4][4];
#pragma unroll
  for (int i = 0; i < 4; i++)
#pragma unroll
    for (int j = 0; j < 4; j++) acc[i][j] = (f32x4){0.f, 0.f, 0.f, 0.f};

  for (int k0 = 0; k0 < 1024; k0 += 64) {
#pragma unroll
    for (int i = 0; i < 4; i++) {
      gl_lds16(Xg + (size_t)i * 32 * 1024 + k0, &Xs[(i * 256 + wave * 64) * 8]);
      gl_lds16(Wg + (size_t)i * 32 * 1024 + k0, &Ws[(i * 256 + wave * 64) * 8]);
    }
    __syncthreads();

#pragma unroll
    for (int ks = 0; ks < 2; ks++) {
      bf16x8 af[4], bfr[4];
#pragma unroll
      for (int i = 0; i < 4; i++) {
        int r = wm * 64 + i * 16 + l16;
        af[i] = *(const bf16x8*)&Xs[r * 64 + ((((ks << 2) | q4)) ^ (r & 7)) * 8];
      }
#pragma unroll
      for (int j = 0; j < 4; j++) {
        int r = wn * 64 + j * 16 + l16;
        bfr[j] = *(const bf16x8*)&Ws[r * 64 + ((((ks << 2) | q4)) ^ (r & 7)) * 8];
      }
#pragma unroll
      for (int i = 0; i < 4; i++)
#pragma unroll
        for (int j = 0; j < 4; j++)
          acc[i][j] = __builtin_amdgcn_mfma_f32_16x16x32_bf16(af[i], bfr[j], acc[i][j], 0, 0, 0);
    }
    __syncthreads();
  }

  // epilogue
#pragma unroll
  for (int j = 0; j < 4; j++) {
    int col = colBase + wn * 64 + j * 16 + l16;
    float bv = bias[col];
#pragma unroll
    for (int i = 0; i < 4; i++) {
      int row0 = rowBase + wm * 64 + i * 16 + q4 * 4;
      if (MODE == 1 || MODE == 2) {
        int b = row0 >> 12, m0 = row0 & 4095;
        int h = col >> 6, dd = col & 63;
        us4v pk;
#pragma unroll
        for (int r = 0; r < 4; r++) {
          float y = acc[i][j][r] + bv;
          if (MODE == 1) y = (y > 0.f) ? (y + 1.f) : __expf(y);
          pk[r] = f2bf(y);
        }
        *(us4v*)&((us*)Yv)[(((size_t)((b * 16 + h) * 64 + dd)) << 12) + m0] = pk;
      } else {
#pragma unroll
        for (int r = 0; r < 4; r++) {
          float y = acc[i][j][r] + bv;
          if (MODE == 0) {
            y = (y > 0.f) ? (y + 1.f) : __expf(y);
            ((us*)Yv)[(size_t)(row0 + r) * 1024 + col] = f2bf(y);
          } else {
            ((float*)Yv)[(size_t)(row0 + r) * 1024 + col] = y;
          }
        }
      }
    }
  }
}

// ---------------------------------------------------------------------------
// kv stage 1: partial kv_t[e][d] = sum_m vt[e][m]*kt[d][m] over a 1024-m slab,
// plus z-partials folded from the kt B-fragments. 256 blocks (bh x 4 splits),
// 4 waves each covering 256 m. LDS tree-reduce, plain stores (no atomics).
// ---------------------------------------------------------------------------
__global__ __launch_bounds__(256) void kv_stage1(const us* __restrict__ kt,
                                                 const us* __restrict__ vt,
                                                 float* __restrict__ part,
                                                 float* __restrict__ zpart) {
  __shared__ float red[4][4096];
  __shared__ float zred[4][64][4];

  const int blk = blockIdx.x;
  const int bh = blk >> 2, split = blk & 3;
  const int t = threadIdx.x;
  const int w = t >> 6, lane = t & 63;
  const int q4 = lane >> 4, l16 = lane & 15;
  const us* ktb = kt + (size_t)bh * 64 * 4096;
  const us* vtb = vt + (size_t)bh * 64 * 4096;
  const int mbeg = split * 1024 + w * 256;

  f32x4 acc[4][4];
#pragma unroll
  for (int i = 0; i < 4; i++)
#pragma unroll
    for (int j = 0; j < 4; j++) acc[i][j] = (f32x4){0.f, 0.f, 0.f, 0.f};
  float zacc[4] = {0.f, 0.f, 0.f, 0.f};

  for (int m0 = mbeg; m0 < mbeg + 256; m0 += 32) {
    bf16x8 af[4], bfr[4];
#pragma unroll
    for (int i = 0; i < 4; i++)
      af[i] = *(const bf16x8*)&vtb[(size_t)(i * 16 + l16) * 4096 + m0 + q4 * 8];
#pragma unroll
    for (int j = 0; j < 4; j++) {
      us8v ub = *(const us8v*)&ktb[(size_t)(j * 16 + l16) * 4096 + m0 + q4 * 8];
      bfr[j] = __builtin_bit_cast(bf16x8, ub);
#pragma unroll
      for (int e = 0; e < 8; e++) zacc[j] += bf2f(ub[e]);
    }
#pragma unroll
    for (int i = 0; i < 4; i++)
#pragma unroll
      for (int j = 0; j < 4; j++)
        acc[i][j] = __builtin_amdgcn_mfma_f32_16x16x32_bf16(af[i], bfr[j], acc[i][j], 0, 0, 0);
  }

#pragma unroll
  for (int i = 0; i < 4; i++)
#pragma unroll
    for (int j = 0; j < 4; j++)
#pragma unroll
      for (int r = 0; r < 4; r++)
        red[w][(i * 16 + q4 * 4 + r) * 64 + j * 16 + l16] = acc[i][j][r];
#pragma unroll
  for (int j = 0; j < 4; j++) zred[w][j * 16 + l16][q4] = zacc[j];
  __syncthreads();

  float* pb = part + (size_t)blk * 4096;
#pragma unroll
  for (int i = 0; i < 16; i++) {
    int idx = t + 256 * i;
    pb[idx] = red[0][idx] + red[1][idx] + red[2][idx] + red[3][idx];
  }
  if (t < 64) {
    float s = 0.f;
#pragma unroll
    for (int w2 = 0; w2 < 4; w2++)
#pragma unroll
      for (int q = 0; q < 4; q++) s += zred[w2][t][q];
    zpart[blk * 64 + t] = s;
  }
}

// stage 2: reduce the 4 split-partials -> kv bf16 + z fp32. 64 blocks.
__global__ __launch_bounds__(256) void kv_stage2(const float* __restrict__ part,
                                                 const float* __restrict__ zpart,
                                                 us* __restrict__ kvb,
                                                 float* __restrict__ z) {
  const int bh = blockIdx.x;
  const int t = threadIdx.x;
  const float* p0 = part + (size_t)bh * 4 * 4096;
#pragma unroll
  for (int i = 0; i < 16; i++) {
    int idx = t + 256 * i;
    float s = p0[idx] + p0[4096 + idx] + p0[8192 + idx] + p0[12288 + idx];
    kvb[(size_t)bh * 4096 + idx] = f2bf(s);
  }
  if (t < 64) {
    const float* zp = zpart + (size_t)bh * 4 * 64;
    z[bh * 64 + t] = zp[t] + zp[64 + t] + zp[128 + t] + zp[192 + t];
  }
}

// ---------------------------------------------------------------------------
// attn[b][n][h*64+e] = (sum_d q[n][d] kv[d][e]) / (q[n]·z + eps), bf16,
// written IN PLACE over q (each block reads exactly the region it writes).
// ---------------------------------------------------------------------------
__global__ __launch_bounds__(256) void attn_kernel(const us* __restrict__ q,
                                                   const us* __restrict__ kvb,
                                                   const float* __restrict__ z,
                                                   us* __restrict__ attn) {
  __shared__ alignas(16) us kvs[64 * 72];
  __shared__ float zs[64];
  __shared__ float invden[256];

  const int bid = blockIdx.x;
  const int bh = bid >> 4, nc = bid & 15;
  const int b = bh >> 4, h = bh & 15;
  const int n0 = nc * 256;
  const int t = threadIdx.x;
  const int wave = t >> 6, lane = t & 63;
  const int q4 = lane >> 4, l16 = lane & 15;

#pragma unroll
  for (int i = 0; i < 2; i++) {
    int chunk = t + 256 * i;          // 0..511
    int e = chunk >> 3, d8 = chunk & 7;
    us8v vv = *(const us8v*)&kvb[(size_t)bh * 4096 + chunk * 8];
    *(us8v*)&kvs[e * 72 + d8 * 8] = vv;
  }
  if (t < 64) zs[t] = z[bh * 64 + t];
  __syncthreads();

  {
    const us* qrow = q + ((size_t)(b * 4096 + n0 + t)) * 1024 + h * 64;
    float s = 0.f;
#pragma unroll
    for (int d0 = 0; d0 < 64; d0 += 8) {
      us8v v = *(const us8v*)(qrow + d0);
#pragma unroll
      for (int j = 0; j < 8; j++) s += bf2f(v[j]) * zs[d0 + j];
    }
    invden[t] = 1.0f / (s + EPS);
  }
  __syncthreads();

  f32x4 acc[4][4];
#pragma unroll
  for (int i = 0; i < 4; i++)
#pragma unroll
    for (int j = 0; j < 4; j++) acc[i][j] = (f32x4){0.f, 0.f, 0.f, 0.f};

  const us* qb = q + ((size_t)(b * 4096 + n0 + wave * 64)) * 1024 + h * 64;
#pragma unroll
  for (int ks = 0; ks < 2; ks++) {
    bf16x8 af[4], bfr[4];
#pragma unroll
    for (int i = 0; i < 4; i++)
      af[i] = *(const bf16x8*)(qb + (size_t)(i * 16 + l16) * 1024 + ks * 32 + q4 * 8);
#pragma unroll
    for (int j = 0; j < 4; j++)
      bfr[j] = *(const bf16x8*)&kvs[(j * 16 + l16) * 72 + ks * 32 + q4 * 8];
#pragma unroll
    for (int i = 0; i < 4; i++)
#pragma unroll
      for (int j = 0; j < 4; j++)
        acc[i][j] = __builtin_amdgcn_mfma_f32_16x16x32_bf16(af[i], bfr[j], acc[i][j], 0, 0, 0);
  }

  us* ab = attn + ((size_t)(b * 4096 + n0 + wave * 64)) * 1024 + h * 64;
#pragma unroll
  for (int i = 0; i < 4; i++)
#pragma unroll
    for (int j = 0; j < 4; j++)
#pragma unroll
      for (int r = 0; r < 4; r++) {
        int rowl = i * 16 + q4 * 4 + r;
        int nl = wave * 64 + rowl;
        int e = j * 16 + l16;
        ab[(size_t)rowl * 1024 + e] = f2bf(acc[i][j][r] * invden[nl]);
      }
}

// ---------------------------------------------------------------------------
extern "C" void kernel_launch(void* const* d_in, const int* in_sizes, int n_in,
                              void* d_out, int out_size, void* d_ws, size_t ws_size,
                              hipStream_t stream) {
  const float* queries = (const float*)d_in[0];
  const float* keys    = (const float*)d_in[1];
  const float* values  = (const float*)d_in[2];
  const float* wq = (const float*)d_in[3];
  const float* bq = (const float*)d_in[4];
  const float* wk = (const float*)d_in[5];
  const float* bk = (const float*)d_in[6];
  const float* wv = (const float*)d_in[7];
  const float* bv = (const float*)d_in[8];
  const float* wo = (const float*)d_in[9];
  const float* bo = (const float*)d_in[10];

  char* ws = (char*)d_ws;
  const size_t TB = (size_t)16384 * 1024 * 2;   // 33.55 MB per big bf16 buffer
  us* A   = (us*)(ws);            // kt, later q/attn
  us* Bb  = (us*)(ws + TB);       // vt, later queries-bf16
  us* Xb  = (us*)(ws + 2 * TB);   // keys/values bf16 scratch
  us* wqb = (us*)(ws + 3 * TB);
  us* wkb = wqb + (size_t)1024 * 1024;
  us* wvb = wkb + (size_t)1024 * 1024;
  us* wob = wvb + (size_t)1024 * 1024;
  float* part  = (float*)(wob + (size_t)1024 * 1024);     // 256*4096 fp32
  float* zpart = part + (size_t)256 * 4096;               // 256*64
  float* z     = zpart + 256 * 64;                        // 4096
  us* kvb      = (us*)(z + 4096);                         // 64*4096 bf16

  const int GRID_IN = 16384 * 1024 / 2048;   // 8192
  const int GRID_W  = 1024 * 1024 / 2048;    // 512

  // weights -> bf16
  conv_bf16<<<GRID_W, 256, 0, stream>>>(wq, wqb);
  conv_bf16<<<GRID_W, 256, 0, stream>>>(wk, wkb);
  conv_bf16<<<GRID_W, 256, 0, stream>>>(wv, wvb);
  conv_bf16<<<GRID_W, 256, 0, stream>>>(wo, wob);

  // K projection
  conv_bf16<<<GRID_IN, 256, 0, stream>>>(keys, Xb);
  proj_gemm<1><<<1024, 256, 0, stream>>>(Xb, wkb, bk, (void*)A);
  // V projection
  conv_bf16<<<GRID_IN, 256, 0, stream>>>(values, Xb);
  proj_gemm<2><<<1024, 256, 0, stream>>>(Xb, wvb, bv, (void*)Bb);
  // kv + z
  kv_stage1<<<256, 256, 0, stream>>>(A, Bb, part, zpart);
  kv_stage2<<<64, 256, 0, stream>>>(part, zpart, kvb, z);
  // Q projection (kt/vt dead; reuse buffers)
  conv_bf16<<<GRID_IN, 256, 0, stream>>>(queries, Bb);
  proj_gemm<0><<<1024, 256, 0, stream>>>(Bb, wqb, bq, (void*)A);
  // attention (in place over q)
  attn_kernel<<<1024, 256, 0, stream>>>(A, kvb, z, A);
  // output projection
  proj_gemm<3><<<1024, 256, 0, stream>>>(A, wob, bo, d_out);
}